// Round 14
// baseline (500.772 us; speedup 1.0000x reference)
//
#include <hip/hip_runtime.h>
#include <hip/hip_bf16.h>

// R14: k_pre taps wasted ~25us (128 blocks, per-l recomputed discretization ->
// now mode-parallel recurrence s<-s*w); conv+glu merged into one k_fused with
// zero Y HBM traffic: conv D[m=h][n=t] per bn (A=Ktap direct L2, B=Toeplitz x
// via 8 shift-aligned reversed copies xrev8 direct L2 -> NO staging LDS),
// y-tile packed into 34KB LDS (verified R6 uint2 pattern), GLU D[m=j][n=t]
// consumes it in-kernel (A=Wbf direct L2, B=y-tile b128), t-pool via in-lane
// sum + shfl_xor reduce + 1 atomic/(j,wave). Dead-t lanes predicated (y=0
// store AND zacc mask — bias-on-zero trap).

#define B_  16
#define T_  354
#define N_  64
#define H_  128
#define NS_ 32
#define BN_ 1024
#define KT_ 512              // Ktap / xrev8 row width (elems)
#define YS_ 136              // y_lds row stride (elems)
#define WB_ ((2 * H_ * H_) / 512)   // 64 Wbf-cast blocks

typedef __attribute__((ext_vector_type(8))) short bf16x8;
typedef __attribute__((ext_vector_type(4))) float f32x4;

static __device__ __forceinline__ unsigned short f32_to_bf16(float f) {
    unsigned int u = __float_as_uint(f);
    unsigned int r = 0x7FFFu + ((u >> 16) & 1u);   // RNE
    return (unsigned short)((u + r) >> 16);
}

// gelu(v) = v * sigmoid(1.595769122*v + 0.071354816*v^3)  (tanh approx, JAX)
static __device__ __forceinline__ float gelu_f(float v) {
    float v2 = v * v;
    float x  = v * fmaf(0.0713548162726f, v2, 1.5957691216057f);
    float sg = 1.0f / (1.0f + __expf(-x));
    return v * sg;
}

// ---------------------------------------------------------------------------
// K0: merged prep, role by blockIdx.x:
//  [0,128):        taps for h=blk — mode-parallel recurrence (32 lanes, each
//                  mode advances s<-s*w over l; 1 exp + 1 sincos per mode).
//                  -> Ktap[h][l] bf16 (fwd, zero-padded), koff[t][h]=b_in*cum.
//  [128,224):      x transpose-cast -> xrevA = xrev8[bn][r=0][i], i = 359 - t
//                  (reversed, 16B-aligned packs; t>=T_ slots are zeros).
//  [224,224+WB_):  W_out f32 -> bf16.
// ---------------------------------------------------------------------------
__global__ __launch_bounds__(512) void k_pre(
        const float* __restrict__ log_dt,
        const float* __restrict__ A_re, const float* __restrict__ A_im,
        const float* __restrict__ C_re, const float* __restrict__ C_im,
        const float* __restrict__ b_in, const float* __restrict__ D,
        const float* __restrict__ x, const float* __restrict__ W_out,
        unsigned short* __restrict__ Ktap, float* __restrict__ koff,
        unsigned short* __restrict__ xrev8, unsigned short* __restrict__ Wbf) {
    __shared__ char smem[48776];                   // union: taps / transpose
    const int blk = blockIdx.x;
    const int tid = threadIdx.x;

    if (blk >= H_ + 96) {                          // ---- Wbf cast ----
        int id = (blk - H_ - 96) * 512 + tid;
        if (id < 2 * H_ * H_) Wbf[id] = f32_to_bf16(W_out[id]);
        return;
    }
    if (blk >= H_) {                               // ---- x transpose ----
        float (*xt)[68] = (float(*)[68])smem;      // 64 x 68, 17.4 KB
        int idx = blk - H_;
        int bt = idx / 6, tt = idx % 6;            // b-index, t-tile
        int r  = tid >> 3, fc = tid & 7;           // row, col-octet
        int t  = tt * 64 + r;
        float4 v0 = make_float4(0.f, 0.f, 0.f, 0.f), v1 = v0;
        if (t < T_) {
            const float* xp = x + ((size_t)bt * T_ + t) * N_ + fc * 8;
            v0 = *(const float4*)xp;
            v1 = *(const float4*)(xp + 4);
        }
        *(float4*)&xt[r][fc * 8]     = v0;         // t>=T_ rows stay zero
        *(float4*)&xt[r][fc * 8 + 4] = v1;
        __syncthreads();
        int n = tid >> 3, tc = tid & 7;
        int ilow = 352 - tt * 64 - tc * 8;         // i = 359 - t, chunk base
        if (ilow >= 0) {
            unsigned short pk[8];
#pragma unroll
            for (int j = 0; j < 8; j++)            // pk[j] <-> t = thigh - j
                pk[j] = f32_to_bf16(xt[tc * 8 + 7 - j][n]);
            int bn = bt * 64 + n;
            *(uint4*)(xrev8 + (size_t)bn * (8 * KT_) + ilow) = *(const uint4*)pk;
        }
        return;
    }

    // ---- taps: mode-parallel recurrence ----
    const int h = blk;
    float* part = (float*)smem;                    // [T_][33], 46.7 KB
    float* sc   = (float*)(smem + 46728);          // [512]
    if (tid < NS_) {
        int m = tid;
        float dt  = expf(log_dt[h]);
        float are = A_re[h * NS_ + m], aim = A_im[h * NS_ + m];
        float dre = are * dt, dim = aim * dt;
        float er  = expf(dre);
        float c1, s1; __sincosf(dim, &s1, &c1);
        float wre = er * c1, wim = er * s1;        // w = exp(dt*A)
        float m_re = wre - 1.0f, m_im = wim;
        float inv  = 1.0f / (are * are + aim * aim);
        float q_re = (m_re * are + m_im * aim) * inv;
        float q_im = (m_im * are - m_re * aim) * inv;
        float c_r = C_re[h * NS_ + m], c_i = C_im[h * NS_ + m];
        float cdre = c_r * q_re - c_i * q_im;      // Cd = C*(w-1)/A
        float cdim = c_r * q_im + c_i * q_re;
        float sre = 1.0f, sim = 0.0f;              // s = exp(dt*A*l), l=0
        for (int l = 0; l < T_; l++) {
            part[l * 33 + m] = cdre * sre - cdim * sim;   // Re(Cd*s)
            float nre = sre * wre - sim * wim;
            float nim = sre * wim + sim * wre;
            sre = nre; sim = nim;
        }
    }
    __syncthreads();
    float val = 0.0f;
    if (tid < T_) {
#pragma unroll 8
        for (int m = 0; m < NS_; m++) val += part[tid * 33 + m];
        val *= 2.0f;
        if (tid == 0) val += D[h];
    }
    sc[tid] = (tid < T_) ? val : 0.0f;
    __syncthreads();
    for (int off = 1; off < 512; off <<= 1) {
        float add = (tid >= off) ? sc[tid - off] : 0.0f;
        __syncthreads();
        sc[tid] += add;
        __syncthreads();
    }
    if (tid < T_) {
        koff[tid * H_ + h] = b_in[h] * sc[tid];
        Ktap[h * KT_ + tid] = f32_to_bf16(val);
    }
}

// ---------------------------------------------------------------------------
// K0b: build shifted copies xrev8[bn][r][i] = xrev8[bn][0][i - r], r=1..7.
// (16-elem window load + in-reg shift; junk in never-read slots is harmless.)
// ---------------------------------------------------------------------------
__global__ void k_cpy(unsigned short* __restrict__ xrev8) {
    int idx = blockIdx.x * 256 + threadIdx.x;      // bn*7*64 ids
    int c8  = idx & 63;
    int rm  = idx >> 6;
    int r   = (rm % 7) + 1;
    int bn  = rm / 7;
    if (bn >= BN_) return;
    const unsigned short* src = xrev8 + (size_t)bn * (8 * KT_);
    union { uint4 v[2]; unsigned short s[16]; } u;
    int base = c8 * 8 - 8;
    u.v[0] = *(const uint4*)(src + base);          // base=-8 reads prior ws (unused slots)
    u.v[1] = *(const uint4*)(src + base + 8);
    unsigned short o[8];
#pragma unroll
    for (int j = 0; j < 8; j++) o[j] = u.s[8 - r + j];
    *(uint4*)(xrev8 + (size_t)bn * (8 * KT_) + r * KT_ + c8 * 8) = *(const uint4*)o;
}

// ---------------------------------------------------------------------------
// K1: fused conv+gelu+GLU+pool.  Block = one bn x one t-tile (128 t).
// Conv D[m=h][n=t]: af = Ktap[h][k] (L2 direct), bf = x[t-k] = xrev8 copy
// r=(t+1)&7 at i=359-t+r+k (16B aligned, L2 direct). No staging LDS.
// Epilogue: y=gelu(win*acc+koff) (0 for t>=T_) -> y_lds[t][h] packed uint2.
// GLU D[m=j][n=t]: wf = Wbf[j][h] (L2 direct), yb = y_lds row (b128).
// z=(g1+bo1)*sig(g2+bo2) pooled over t in-lane (masked t<T_), shfl_xor
// reduce over the 16-lane t-group, atomicAdd from l16==0 lanes.
// ---------------------------------------------------------------------------
__global__ __launch_bounds__(256, 3) void k_fused(
        const unsigned short* __restrict__ xrev8,  // [bn][8][KT_]
        const unsigned short* __restrict__ Ktap,   // [128][KT_]
        const float* __restrict__ koff,            // [354][128]
        const float* __restrict__ W_in,
        const unsigned short* __restrict__ Wbf,    // [256][128]
        const float* __restrict__ b_out,
        float* __restrict__ node_sum) {
    __shared__ unsigned short y_lds[128 * YS_];    // 34.8 KB

    const int tid  = threadIdx.x;
    const int w    = tid >> 6;
    const int lane = tid & 63;
    const int q    = lane >> 4;
    const int l16  = lane & 15;
    const int bn   = blockIdx.x;
    const int ti   = blockIdx.y;
    const int t0   = ti * 128;
    const int wm   = (w & 1) * 64;                 // h quadrant
    const int wn   = (w >> 1) * 64;                // t quadrant
    const int nkb  = ti + 1;

    // hoisted conv operand pointers
    const unsigned short* aptr[4];
#pragma unroll
    for (int mt = 0; mt < 4; mt++)
        aptr[mt] = Ktap + (size_t)(wm + mt * 16 + l16) * KT_ + q * 8;
    const unsigned short* bptr[4];
#pragma unroll
    for (int nt = 0; nt < 4; nt++) {
        int t = t0 + wn + nt * 16 + l16;
        int r = (t + 1) & 7;                       // alignment copy select
        bptr[nt] = xrev8 + (size_t)bn * (8 * KT_) + r * KT_ + (359 - t + r) + q * 8;
    }

    // ---- conv: D[m=h][n=t] ----
    f32x4 cacc[4][4];
#pragma unroll
    for (int mt = 0; mt < 4; mt++)
#pragma unroll
        for (int nt = 0; nt < 4; nt++) cacc[mt][nt] = (f32x4){0.f, 0.f, 0.f, 0.f};

    for (int kb = 0; kb < nkb; kb++) {
#pragma unroll
        for (int ks = 0; ks < 4; ks++) {
            const int off = kb * 128 + ks * 32;
            bf16x8 af[4], bf[4];
#pragma unroll
            for (int mt = 0; mt < 4; mt++) af[mt] = *(const bf16x8*)(aptr[mt] + off);
#pragma unroll
            for (int nt = 0; nt < 4; nt++) bf[nt] = *(const bf16x8*)(bptr[nt] + off);
#pragma unroll
            for (int mt = 0; mt < 4; mt++)
#pragma unroll
                for (int nt = 0; nt < 4; nt++)
                    cacc[mt][nt] = __builtin_amdgcn_mfma_f32_16x16x32_bf16(
                        af[mt], bf[nt], cacc[mt][nt], 0, 0, 0);
        }
    }

    // ---- epilogue: gelu -> y_lds[t][h] (packed 4-h uint2; 0 for t>=T_) ----
#pragma unroll
    for (int mt = 0; mt < 4; mt++) {
        const int h0 = wm + mt * 16 + q * 4;
        const float4 wi = *(const float4*)(W_in + h0);
#pragma unroll
        for (int nt = 0; nt < 4; nt++) {
            const int tl = wn + nt * 16 + l16;
            const int t  = t0 + tl;
            const int tc = (t < T_) ? t : (T_ - 1);
            const float4 ko = *(const float4*)(koff + tc * H_ + h0);
            unsigned short pk[4];
#pragma unroll
            for (int rr = 0; rr < 4; rr++) {
                float v = fmaf(cacc[mt][nt][rr], (&wi.x)[rr], (&ko.x)[rr]);
                pk[rr] = (t < T_) ? f32_to_bf16(gelu_f(v)) : (unsigned short)0;
            }
            *(uint2*)&y_lds[tl * YS_ + h0] = *(const uint2*)pk;
        }
    }
    __syncthreads();

    // ---- GLU: D[m=j][n=t], wave w owns 16-t slices, 2 passes ----
    float zacc[8][4];
#pragma unroll
    for (int mp = 0; mp < 8; mp++)
#pragma unroll
        for (int rr = 0; rr < 4; rr++) zacc[mp][rr] = 0.0f;

#pragma unroll
    for (int pass = 0; pass < 2; pass++) {
        const int tb = pass * 64 + w * 16;
        const bool tv = (t0 + tb + l16) < T_;
        f32x4 gacc[16];
#pragma unroll
        for (int m = 0; m < 16; m++) gacc[m] = (f32x4){0.f, 0.f, 0.f, 0.f};

#pragma unroll
        for (int ks = 0; ks < 4; ks++) {
            const bf16x8 yb = *(const bf16x8*)&y_lds[(tb + l16) * YS_ + ks * 32 + q * 8];
#pragma unroll
            for (int mg = 0; mg < 4; mg++) {       // 4 wf at a time (reg cap)
                bf16x8 wf[4];
#pragma unroll
                for (int mi = 0; mi < 4; mi++)
                    wf[mi] = *(const bf16x8*)(Wbf
                        + (size_t)((mg * 4 + mi) * 16 + l16) * H_ + ks * 32 + q * 8);
#pragma unroll
                for (int mi = 0; mi < 4; mi++)
                    gacc[mg * 4 + mi] = __builtin_amdgcn_mfma_f32_16x16x32_bf16(
                        wf[mi], yb, gacc[mg * 4 + mi], 0, 0, 0);
            }
        }

#pragma unroll
        for (int mp = 0; mp < 8; mp++) {
            const float4 bo1 = *(const float4*)(b_out + mp * 16 + q * 4);
            const float4 bo2 = *(const float4*)(b_out + 128 + mp * 16 + q * 4);
#pragma unroll
            for (int rr = 0; rr < 4; rr++) {
                float a  = gacc[mp][rr] + (&bo1.x)[rr];
                float bs = gacc[mp + 8][rr] + (&bo2.x)[rr];
                float sg = 1.0f / (1.0f + __expf(-bs));
                if (tv) zacc[mp][rr] += a * sg;
            }
        }
    }

    // ---- reduce over the 16-lane t-group, flush ----
#pragma unroll
    for (int mp = 0; mp < 8; mp++)
#pragma unroll
        for (int rr = 0; rr < 4; rr++) {
            float v = zacc[mp][rr];
            v += __shfl_xor(v, 1);
            v += __shfl_xor(v, 2);
            v += __shfl_xor(v, 4);
            v += __shfl_xor(v, 8);
            if (l16 == 0)
                atomicAdd(&node_sum[bn * H_ + mp * 16 + q * 4 + rr], v);
        }
}

// ---------------------------------------------------------------------------
// K2: logits[b] = (1/(T*N)) * sum_{n,h} node_sum[b*64+n][h] * W_cls[h] + b_cls
// ---------------------------------------------------------------------------
__global__ void k_cls(const float* __restrict__ node_sum,
                      const float* __restrict__ W_cls, const float* __restrict__ b_cls,
                      float* __restrict__ out) {
    const int b = blockIdx.x, tid = threadIdx.x;
    float s = 0.0f;
    for (int i = tid; i < N_ * H_; i += 256)
        s += node_sum[b * (N_ * H_) + i] * W_cls[i & (H_ - 1)];
    __shared__ float red[256];
    red[tid] = s;
    __syncthreads();
    for (int off = 128; off > 0; off >>= 1) {
        if (tid < off) red[tid] += red[tid + off];
        __syncthreads();
    }
    if (tid == 0) out[b] = red[0] * (1.0f / (354.0f * 64.0f)) + b_cls[0];
}

// ---------------------------------------------------------------------------
extern "C" void kernel_launch(void* const* d_in, const int* in_sizes, int n_in,
                              void* d_out, int out_size, void* d_ws, size_t ws_size,
                              hipStream_t stream) {
    const float* x      = (const float*)d_in[0];
    const float* W_in   = (const float*)d_in[1];
    const float* b_in   = (const float*)d_in[2];
    const float* log_dt = (const float*)d_in[3];
    const float* A_re   = (const float*)d_in[4];
    const float* A_im   = (const float*)d_in[5];
    const float* C_re   = (const float*)d_in[6];
    const float* C_im   = (const float*)d_in[7];
    const float* D      = (const float*)d_in[8];
    const float* W_out  = (const float*)d_in[9];
    const float* b_out  = (const float*)d_in[10];
    const float* W_cls  = (const float*)d_in[11];
    const float* b_cls  = (const float*)d_in[12];

    char* ws = (char*)d_ws;
    // [node_sum 512K][Ktap 128K][xrev8 8M] contiguous -> ONE memset
    float*          node_sum = (float*)(ws + 0);                  //  524288 B
    unsigned short* Ktap     = (unsigned short*)(ws + 524288);    //  131072 B
    unsigned short* xrev8    = (unsigned short*)(ws + 655360);    // 8388608 B
    float*          koff     = (float*)(ws + 9043968);            //  181248 B
    unsigned short* Wbf      = (unsigned short*)(ws + 9225216);   //   65536 B

    hipMemsetAsync(ws, 0, 9043968, stream);
    k_pre<<<dim3(H_ + 96 + WB_), dim3(512), 0, stream>>>(
        log_dt, A_re, A_im, C_re, C_im, b_in, D, x, W_out, Ktap, koff, xrev8, Wbf);
    k_cpy<<<dim3((BN_ * 7 * 64) / 256), dim3(256), 0, stream>>>(xrev8);
    k_fused<<<dim3(BN_, 3), dim3(256), 0, stream>>>(
        xrev8, Ktap, koff, W_in, Wbf, b_out, node_sum);
    k_cls<<<dim3(B_), dim3(256), 0, stream>>>(node_sum, W_cls, b_cls, (float*)d_out);
}

// Round 15
// 259.870 us; speedup vs baseline: 1.9270x; 1.9270x over previous
//
#include <hip/hip_runtime.h>
#include <hip/hip_bf16.h>

// R15: R14's all-direct-L2 design failed (per-lane row-scattered B reads on an
// 8MB table missed L2 -> FETCH 182MB; 160+ live acc/frag regs -> 365MB spill
// WRITE). Rebuild from R13 (best structure) with ONE change: k_conv t-pair ->
// t-QUAD. All 4 t's in a quad share the same x kb-tiles, so each 16-load
// stage phase now feeds 128 MFMA (was 64). cacc=128 acc-regs -> (256,2); K
// frags stay direct-from-L2 (1MB Krev, proven in R13), x dbuf + LDS-bounce
// coalesced Y stores verbatim. k_pre/k_glu/k_cls byte-identical to R13.

#define B_  16
#define T_  354
#define N_  64
#define H_  128
#define NS_ 32
#define BN_ (B_*N_)          // 1024 sequences
#define TP_ 384              // padded tau range for xbf rows
#define KW_ 512              // padded Krev row length
#define PAD_ 136             // LDS row stride (bf16 elems)
#define GT_ 16               // t's per k_glu block
#define NGT_ ((T_ + GT_ - 1) / GT_)   // 23
#define WB_ ((2 * H_ * H_) / 512)     // 64 Wbf-cast blocks

typedef __attribute__((ext_vector_type(8))) short bf16x8;
typedef __attribute__((ext_vector_type(4))) float f32x4;

static __device__ __forceinline__ unsigned short f32_to_bf16(float f) {
    unsigned int u = __float_as_uint(f);
    unsigned int r = 0x7FFFu + ((u >> 16) & 1u);   // RNE
    return (unsigned short)((u + r) >> 16);
}

// async global->LDS, 4 B per lane: one 256 B row per instruction.
static __device__ __forceinline__ void gload_lds4(const void* g, void* l) {
    __builtin_amdgcn_global_load_lds(
        (const __attribute__((address_space(1))) unsigned int*)g,
        (__attribute__((address_space(3))) unsigned int*)l, 4, 0, 0);
}

// gelu(v) = v * sigmoid(1.595769122*v + 0.071354816*v^3)  (tanh approx, JAX)
static __device__ __forceinline__ float gelu_f(float v) {
    float v2 = v * v;
    float x  = v * fmaf(0.0713548162726f, v2, 1.5957691216057f);
    float sg = 1.0f / (1.0f + __expf(-x));
    return v * sg;
}

// ---------------------------------------------------------------------------
// K0: merged prep, role by blockIdx.x:
//  [0,128):        S4D taps for h=blockIdx (+ Krev 8 copies + koff scan)
//  [128,224):      x transpose-cast via LDS (64t x 64n tile)
//  [224,224+WB_):  W_out f32 -> bf16
// ---------------------------------------------------------------------------
__global__ __launch_bounds__(512) void k_pre(
        const float* __restrict__ log_dt,
        const float* __restrict__ A_re, const float* __restrict__ A_im,
        const float* __restrict__ C_re, const float* __restrict__ C_im,
        const float* __restrict__ b_in, const float* __restrict__ D,
        const float* __restrict__ x, const float* __restrict__ W_out,
        unsigned short* __restrict__ Krev, float* __restrict__ koff,
        unsigned short* __restrict__ xbf, unsigned short* __restrict__ Wbf) {
    const int blk = blockIdx.x;
    const int tid = threadIdx.x;

    if (blk >= H_ + 96) {                          // ---- Wbf cast ----
        int id = (blk - H_ - 96) * 512 + tid;
        if (id < 2 * H_ * H_) Wbf[id] = f32_to_bf16(W_out[id]);
        return;
    }
    if (blk >= H_) {                               // ---- x transpose ----
        __shared__ float xt[64][68];               // +4 pad
        int idx = blk - H_;
        int bt = idx / 6, tt = idx % 6;            // b-index, t-tile
        int r  = tid >> 3, fc = tid & 7;           // row, col-octet
        int t  = tt * 64 + r;
        float4 v0 = make_float4(0.f, 0.f, 0.f, 0.f), v1 = v0;
        if (t < T_) {
            const float* xp = x + ((size_t)bt * T_ + t) * N_ + fc * 8;
            v0 = *(const float4*)xp;
            v1 = *(const float4*)(xp + 4);
        }
        *(float4*)&xt[r][fc * 8]     = v0;
        *(float4*)&xt[r][fc * 8 + 4] = v1;
        __syncthreads();
        int n = tid >> 3, tc = tid & 7;
        unsigned short pk[8];
#pragma unroll
        for (int k = 0; k < 8; k++) pk[k] = f32_to_bf16(xt[tc * 8 + k][n]);
        *(uint4*)(xbf + (size_t)(bt * 64 + n) * TP_ + tt * 64 + tc * 8)
            = *(const uint4*)pk;
        return;
    }

    // ---- taps ----
    const int h = blk;
    const int l = tid;
    float val = 0.0f;
    if (l < T_) {
        float dt = expf(log_dt[h]);
        float fl = (float)l;
#pragma unroll 4
        for (int m = 0; m < NS_; m++) {
            float are = A_re[h * NS_ + m], aim = A_im[h * NS_ + m];
            float dre = are * dt, dim = aim * dt;
            float er  = expf(dre);
            float c1, s1; __sincosf(dim, &s1, &c1);
            float e_re = er * c1, e_im = er * s1;
            float m_re = e_re - 1.0f, m_im = e_im;
            float inv  = 1.0f / (are * are + aim * aim);
            float q_re = (m_re * are + m_im * aim) * inv;
            float q_im = (m_im * are - m_re * aim) * inv;
            float c_r = C_re[h * NS_ + m], c_i = C_im[h * NS_ + m];
            float cdre = c_r * q_re - c_i * q_im;
            float cdim = c_r * q_im + c_i * q_re;
            float el = expf(dre * fl);
            float cl, sl; __sincosf(dim * fl, &sl, &cl);
            val += el * (cdre * cl - cdim * sl);
        }
        val *= 2.0f;
        if (l == 0) val += D[h];
    }

    __shared__ float sc[512];
    sc[l] = (l < T_) ? val : 0.0f;
    __syncthreads();
    for (int off = 1; off < 512; off <<= 1) {
        float add = (l >= off) ? sc[l - off] : 0.0f;
        __syncthreads();
        sc[l] += add;
        __syncthreads();
    }

    if (l < T_) {
        koff[l * H_ + h] = b_in[h] * sc[l];
        unsigned short bv = f32_to_bf16(val);
#pragma unroll
        for (int r = 0; r < 8; r++)
            Krev[((size_t)r * H_ + h) * KW_ + (T_ - 1 - l) + r] = bv;
    }
}

// ---------------------------------------------------------------------------
// K1: conv + gelu -> Y[q][h].  Block = 64 bn x 128 h x t-QUAD (t0..t0+3).
// kb-outer with x LDS double-buffer: the x-tile is t-independent, so one
// 16-load stage phase feeds 4 t's x 32 MFMA = 128 MFMA.  K a-frags direct
// from L2-hot Krev (copy-select cp=(-L)&7, 16B aligned, statically indexed,
// consumed immediately).  Out-of-range (t>=T_ / tau0>t) reads land in the
// zero-padding (max offset 491 < KW_=512) -> contribute 0; stores predicated.
// Epilogue per t: gelu -> y-tile in buf0 -> coalesced 256B-row stores.
// ---------------------------------------------------------------------------
__global__ __launch_bounds__(256, 2) void k_conv(
        const unsigned short* __restrict__ xbf,    // [1024][TP_]
        const unsigned short* __restrict__ Krev,   // [8][128][KW_]
        const float* __restrict__ koff,            // [354][128]
        const float* __restrict__ W_in,
        unsigned short* __restrict__ Y) {          // [q][h]
    __shared__ unsigned short x_lds[2][64 * PAD_]; // 2 x 17 KB

    const int tid  = threadIdx.x;
    const int w    = tid >> 6;
    const int lane = tid & 63;
    const int q    = lane >> 4;
    const int l16  = lane & 15;
    const int bn0  = blockIdx.x * 64;
    const int t0   = blockIdx.y * 4;               // t-quad
    const int nkb  = ((t0 + 3) >> 7) + 1;

    float win[2][4];
#pragma unroll
    for (int mt = 0; mt < 2; mt++)
#pragma unroll
        for (int rr = 0; rr < 4; rr++)
            win[mt][rr] = W_in[32 * w + 16 * mt + 4 * q + rr];

    f32x4 cacc[4][2][4];                           // [tt][mt][nt] = 128 acc
#pragma unroll
    for (int tt = 0; tt < 4; tt++)
#pragma unroll
        for (int mt = 0; mt < 2; mt++)
#pragma unroll
            for (int nt = 0; nt < 4; nt++)
                cacc[tt][mt][nt] = (f32x4){0.f, 0.f, 0.f, 0.f};

    // prologue: stage kb=0 into buf0
#pragma unroll
    for (int i = 0; i < 16; i++) {
        int r = w * 16 + i;
        gload_lds4(xbf + (size_t)(bn0 + r) * TP_ + lane * 2,
                   &x_lds[0][r * PAD_]);
    }

    for (int kb = 0; kb < nkb; kb++) {
        const int tau0 = kb << 7;
        __syncthreads();                           // drain stage(kb); buf safe
        if (kb + 1 < nkb) {                        // prefetch kb+1 (no wait)
            const int taun = (kb + 1) << 7;
#pragma unroll
            for (int i = 0; i < 16; i++) {
                int r = w * 16 + i;
                gload_lds4(xbf + (size_t)(bn0 + r) * TP_ + taun + lane * 2,
                           &x_lds[(kb + 1) & 1][r * PAD_]);
            }
        }
        const unsigned short* xb = x_lds[kb & 1];

#pragma unroll
        for (int tt = 0; tt < 4; tt++) {
            const int t  = t0 + tt;
            const int L  = 353 - t + tau0;         // >= -2; cp fixes align
            const int cp = (-L) & 7;               // 16B-aligned copy
            const unsigned short* kbase = Krev + (size_t)cp * H_ * KW_ + (L + cp);

            bf16x8 kf[4][2];                       // short-lived, static idx
#pragma unroll
            for (int ks = 0; ks < 4; ks++)
#pragma unroll
                for (int mt = 0; mt < 2; mt++)
                    kf[ks][mt] = *(const bf16x8*)(kbase
                        + (size_t)(32 * w + 16 * mt + l16) * KW_ + ks * 32 + q * 8);

#pragma unroll
            for (int ks = 0; ks < 4; ks++) {
                bf16x8 bf[4];
#pragma unroll
                for (int nt = 0; nt < 4; nt++)
                    bf[nt] = *(const bf16x8*)&xb[(16 * nt + l16) * PAD_ + ks * 32 + q * 8];
#pragma unroll
                for (int mt = 0; mt < 2; mt++)
#pragma unroll
                    for (int nt = 0; nt < 4; nt++)
                        cacc[tt][mt][nt] = __builtin_amdgcn_mfma_f32_16x16x32_bf16(
                            kf[ks][mt], bf[nt], cacc[tt][mt][nt], 0, 0, 0);
            }
        }
    }

    // ---- epilogue per t: gelu -> y-tile [bn][h] in buf0 -> coalesced store
#pragma unroll
    for (int tt = 0; tt < 4; tt++) {
        const int t = t0 + tt;
        if (t >= T_) break;                        // block-uniform
        __syncthreads();                           // buf free of readers
#pragma unroll
        for (int mt = 0; mt < 2; mt++) {
            int h0 = 32 * w + 16 * mt + 4 * q;
#pragma unroll
            for (int nt = 0; nt < 4; nt++) {
                unsigned short pk[4];
#pragma unroll
                for (int rr = 0; rr < 4; rr++) {
                    float v = fmaf(cacc[tt][mt][nt][rr], win[mt][rr],
                                   koff[t * H_ + h0 + rr]);
                    pk[rr] = f32_to_bf16(gelu_f(v));
                }
                *(uint2*)&x_lds[0][(16 * nt + l16) * PAD_ + h0] = *(const uint2*)pk;
            }
        }
        __syncthreads();
#pragma unroll
        for (int i = 0; i < 4; i++) {
            int c    = i * 256 + tid;
            int row  = c >> 4;
            int col8 = (c & 15) * 8;
            uint4 v = *(const uint4*)&x_lds[0][row * PAD_ + col8];
            *(uint4*)(Y + ((size_t)t * BN_ + bn0 + row) * H_ + col8) = v;
        }
    }
}

// ---------------------------------------------------------------------------
// K2: GLU GEMM + t-pool.  D[m=j][n=bn], A = W frags (VGPR-persistent, 16
// j-pairs per wave), B = Y-tile in double-buffered LDS: stage(t+1) issued
// after the barrier, before compute(t).  One barrier per t.  GT_=16.
// ---------------------------------------------------------------------------
__global__ __launch_bounds__(256, 4) void k_glu(
        const unsigned short* __restrict__ Y,      // [q][h]
        const unsigned short* __restrict__ Wbf,    // [256][128]
        const float* __restrict__ b_out,
        float* __restrict__ node_sum) {
    __shared__ unsigned short Yt[2][64 * PAD_];    // 2 x 17 KB

    const int tid  = threadIdx.x;
    const int w    = tid >> 6;
    const int lane = tid & 63;
    const int q    = lane >> 4;
    const int l16  = lane & 15;
    const int jg   = blockIdx.x & 1;
    const int bn0  = (blockIdx.x >> 1) * 64;
    const int tg0  = blockIdx.y * GT_;
    const int jlow = jg * 64 + w * 16;
    const int jhigh = jlow + 128;

    bf16x8 wfrag[2][4];                            // [low/high][ks]
#pragma unroll
    for (int ks = 0; ks < 4; ks++) {
        wfrag[0][ks] = *(const bf16x8*)(Wbf + (size_t)(jlow  + l16) * H_ + ks * 32 + q * 8);
        wfrag[1][ks] = *(const bf16x8*)(Wbf + (size_t)(jhigh + l16) * H_ + ks * 32 + q * 8);
    }
    float bo1[4], bo2[4];
#pragma unroll
    for (int rr = 0; rr < 4; rr++) {
        bo1[rr] = b_out[jlow  + 4 * q + rr];
        bo2[rr] = b_out[jhigh + 4 * q + rr];
    }

    f32x4 zacc[4];
#pragma unroll
    for (int nt = 0; nt < 4; nt++) zacc[nt] = (f32x4){0.f, 0.f, 0.f, 0.f};

    // prologue: stage t=tg0 into buf0 (tg0 < T_ always)
#pragma unroll
    for (int i = 0; i < 16; i++) {
        int r = w * 16 + i;
        gload_lds4(Y + ((size_t)tg0 * BN_ + bn0 + r) * H_ + lane * 2,
                   &Yt[0][r * PAD_]);
    }

    for (int g = 0; g < GT_; g++) {
        const int t = tg0 + g;
        if (t >= T_) break;                        // block-uniform
        __syncthreads();                           // drain stage(t); buf safe
        if (g + 1 < GT_ && t + 1 < T_) {           // prefetch t+1 (no wait)
#pragma unroll
            for (int i = 0; i < 16; i++) {
                int r = w * 16 + i;
                gload_lds4(Y + ((size_t)(t + 1) * BN_ + bn0 + r) * H_ + lane * 2,
                           &Yt[(g + 1) & 1][r * PAD_]);
            }
        }
        const unsigned short* buf = Yt[g & 1];

        f32x4 gacc[2][4];
#pragma unroll
        for (int mt = 0; mt < 2; mt++)
#pragma unroll
            for (int nt = 0; nt < 4; nt++) gacc[mt][nt] = (f32x4){0.f, 0.f, 0.f, 0.f};

#pragma unroll
        for (int ks = 0; ks < 4; ks++) {
            bf16x8 yf[4];
#pragma unroll
            for (int nt = 0; nt < 4; nt++)
                yf[nt] = *(const bf16x8*)&buf[(16 * nt + l16) * PAD_ + ks * 32 + q * 8];
#pragma unroll
            for (int mt = 0; mt < 2; mt++)
#pragma unroll
                for (int nt = 0; nt < 4; nt++)
                    gacc[mt][nt] = __builtin_amdgcn_mfma_f32_16x16x32_bf16(
                        wfrag[mt][ks], yf[nt], gacc[mt][nt], 0, 0, 0);
        }

#pragma unroll
        for (int nt = 0; nt < 4; nt++)
#pragma unroll
            for (int rr = 0; rr < 4; rr++) {
                float a  = gacc[0][nt][rr] + bo1[rr];
                float bs = gacc[1][nt][rr] + bo2[rr];
                float sg = 1.0f / (1.0f + __expf(-bs));
                zacc[nt][rr] += a * sg;
            }
    }

    // flush: lanes sharing a 64B line (16 consecutive j at fixed bn)
#pragma unroll
    for (int nt = 0; nt < 4; nt++)
#pragma unroll
        for (int rr = 0; rr < 4; rr++) {
            int bn = bn0 + 16 * nt + l16;
            int j  = jlow + 4 * q + rr;
            atomicAdd(&node_sum[bn * H_ + j], zacc[nt][rr]);
        }
}

// ---------------------------------------------------------------------------
// K3: logits[b] = (1/(T*N)) * sum_{n,h} node_sum[b*64+n][h] * W_cls[h] + b_cls
// ---------------------------------------------------------------------------
__global__ void k_cls(const float* __restrict__ node_sum,
                      const float* __restrict__ W_cls, const float* __restrict__ b_cls,
                      float* __restrict__ out) {
    const int b = blockIdx.x, tid = threadIdx.x;
    float s = 0.0f;
    for (int i = tid; i < N_ * H_; i += 256)
        s += node_sum[b * (N_ * H_) + i] * W_cls[i & (H_ - 1)];
    __shared__ float red[256];
    red[tid] = s;
    __syncthreads();
    for (int off = 128; off > 0; off >>= 1) {
        if (tid < off) red[tid] += red[tid + off];
        __syncthreads();
    }
    if (tid == 0) out[b] = red[0] * (1.0f / (354.0f * 64.0f)) + b_cls[0];
}

// ---------------------------------------------------------------------------
extern "C" void kernel_launch(void* const* d_in, const int* in_sizes, int n_in,
                              void* d_out, int out_size, void* d_ws, size_t ws_size,
                              hipStream_t stream) {
    const float* x      = (const float*)d_in[0];
    const float* W_in   = (const float*)d_in[1];
    const float* b_in   = (const float*)d_in[2];
    const float* log_dt = (const float*)d_in[3];
    const float* A_re   = (const float*)d_in[4];
    const float* A_im   = (const float*)d_in[5];
    const float* C_re   = (const float*)d_in[6];
    const float* C_im   = (const float*)d_in[7];
    const float* D      = (const float*)d_in[8];
    const float* W_out  = (const float*)d_in[9];
    const float* b_out  = (const float*)d_in[10];
    const float* W_cls  = (const float*)d_in[11];
    const float* b_cls  = (const float*)d_in[12];

    char* ws = (char*)d_ws;
    // [node_sum 512K][Krev 1M] contiguous -> ONE memset; rest fully written
    float*          node_sum = (float*)(ws + 0);                  //   524288 B
    unsigned short* Krev     = (unsigned short*)(ws + 524288);    //  1048576 B
    float*          koff     = (float*)(ws + 1572864);            //   181248 B
    unsigned short* xbf      = (unsigned short*)(ws + 1754112);   //   786432 B
    unsigned short* Wbf      = (unsigned short*)(ws + 2540544);   //    65536 B
    unsigned short* Y        = (unsigned short*)(ws + 2606080);   // 92798976 B

    hipMemsetAsync(ws, 0, 1572864, stream);
    k_pre<<<dim3(H_ + 96 + WB_), dim3(512), 0, stream>>>(
        log_dt, A_re, A_im, C_re, C_im, b_in, D, x, W_out, Krev, koff, xbf, Wbf);
    k_conv<<<dim3(BN_ / 64, (T_ + 3) / 4), dim3(256), 0, stream>>>(
        xbf, Krev, koff, W_in, Y);
    k_glu<<<dim3(2 * BN_ / 64, NGT_), dim3(256), 0, stream>>>(
        Y, Wbf, b_out, node_sum);
    k_cls<<<dim3(B_), dim3(256), 0, stream>>>(node_sum, W_cls, b_cls, (float*)d_out);
}